// Round 1
// baseline (668.395 us; speedup 1.0000x reference)
//
#include <hip/hip_runtime.h>
#include <hip/hip_bf16.h>
#include <stdint.h>

// AttentionGate on MI355X.
// Pipeline: K1 (MFMA bf16 convs + group stats) -> K1.5 (fold stats) ->
//           K2 (leaky+psi dot + psi stats) -> K3 (sigmoid GN + x*psi).
// ws layout: wsg bf16 [2][N][64] (64MiB) | wsx same (64MiB) | p_pre f32 (2MiB)
//            | stats 256B | psiStats 16B | cst 2KiB   (total ~136.32 MB)

#define DEV __device__ __forceinline__

typedef __attribute__((ext_vector_type(8))) short short8;
typedef __attribute__((ext_vector_type(4))) float floatx4;

constexpr int CG = 128;            // g in-channels
constexpr int CX = 64;             // x in-channels
constexpr int CO = 64;             // inter channels
constexpr int NSP = 64 * 64 * 64;  // 262144 spatial per batch
constexpr int GROUPS = 8;
constexpr float EPS = 1e-5f;

constexpr int LGS = 136;  // lG row stride (ushort): 128+8 pad -> 272B (16B mult)
constexpr int LXS = 72;   // lX row stride: 64+8 pad -> 144B
constexpr int TS  = 64;   // spatial tile
constexpr int TPB = 8;    // tiles per block -> block spans 512 spatial

DEV unsigned short f2bf(float f) {
  union { float f; uint32_t u; } v; v.f = f;
  uint32_t r = v.u + 0x7fffu + ((v.u >> 16) & 1u);
  return (unsigned short)(r >> 16);
}
DEV float bf2f(uint32_t h) {
  union { uint32_t u; float f; } v; v.u = h << 16;
  return v.f;
}

// ---------------- K1: convs via MFMA + group stats ----------------
__global__ __launch_bounds__(256, 4)
void k1_conv(const float* __restrict__ g, const float* __restrict__ x,
             const float* __restrict__ wg, const float* __restrict__ wx,
             unsigned short* __restrict__ outg, unsigned short* __restrict__ outx,
             float* __restrict__ stats)
{
  __shared__ unsigned short lG[TS * LGS];
  __shared__ unsigned short lX[TS * LXS];

  const int tid  = threadIdx.x;
  const int wave = tid >> 6;
  const int lane = tid & 63;
  const int l16  = lane & 15;
  const int quad = lane >> 4;
  const int batch = blockIdx.x >> 9;              // 512 blocks per batch
  const int sblk  = (blockIdx.x & 511) * (TS * TPB);

  // A-fragments: lane holds A[m=lane&15][k=quad*8+j]  (guide §3, m120)
  const int ocb = wave * 16;
  short8 fg[4], fx[2];
  {
    const float* wr = wg + (size_t)(ocb + l16) * CG + quad * 8;
#pragma unroll
    for (int kk = 0; kk < 4; ++kk) {
      float4 u0 = *(const float4*)(wr + kk * 32);
      float4 u1 = *(const float4*)(wr + kk * 32 + 4);
      fg[kk][0] = (short)f2bf(u0.x); fg[kk][1] = (short)f2bf(u0.y);
      fg[kk][2] = (short)f2bf(u0.z); fg[kk][3] = (short)f2bf(u0.w);
      fg[kk][4] = (short)f2bf(u1.x); fg[kk][5] = (short)f2bf(u1.y);
      fg[kk][6] = (short)f2bf(u1.z); fg[kk][7] = (short)f2bf(u1.w);
    }
    const float* xr = wx + (size_t)(ocb + l16) * CX + quad * 8;
#pragma unroll
    for (int kk = 0; kk < 2; ++kk) {
      float4 u0 = *(const float4*)(xr + kk * 32);
      float4 u1 = *(const float4*)(xr + kk * 32 + 4);
      fx[kk][0] = (short)f2bf(u0.x); fx[kk][1] = (short)f2bf(u0.y);
      fx[kk][2] = (short)f2bf(u0.z); fx[kk][3] = (short)f2bf(u0.w);
      fx[kk][4] = (short)f2bf(u1.x); fx[kk][5] = (short)f2bf(u1.y);
      fx[kk][6] = (short)f2bf(u1.z); fx[kk][7] = (short)f2bf(u1.w);
    }
  }

  float sumG = 0.f, sqG = 0.f, sumX = 0.f, sqX = 0.f;

  const int gq = tid >> 3;   // G staging: channel quad 0..31
  const int gh = tid & 7;    // spatial octet
  const int xq = tid >> 4;   // X staging: channel quad 0..15
  const int xh = tid & 15;   // spatial quad

  for (int t = 0; t < TPB; ++t) {
    const int s0 = sblk + t * TS;
    __syncthreads();  // previous tile's LDS reads complete

    // stage G tile: 128ch x 64sp, fp32 -> bf16, transposed [s][c]
    {
      float vv[4][8];
      const float* gp = g + ((size_t)(batch * CG + gq * 4)) * NSP + s0 + gh * 8;
#pragma unroll
      for (int dc = 0; dc < 4; ++dc) {
        float4 a = *(const float4*)(gp + (size_t)dc * NSP);
        float4 b = *(const float4*)(gp + (size_t)dc * NSP + 4);
        vv[dc][0] = a.x; vv[dc][1] = a.y; vv[dc][2] = a.z; vv[dc][3] = a.w;
        vv[dc][4] = b.x; vv[dc][5] = b.y; vv[dc][6] = b.z; vv[dc][7] = b.w;
      }
#pragma unroll
      for (int j = 0; j < 8; ++j) {
        ushort4 o;
        o.x = f2bf(vv[0][j]); o.y = f2bf(vv[1][j]);
        o.z = f2bf(vv[2][j]); o.w = f2bf(vv[3][j]);
        *(ushort4*)&lG[(gh * 8 + j) * LGS + gq * 4] = o;
      }
    }
    // stage X tile: 64ch x 64sp
    {
      float vv[4][4];
      const float* xp = x + ((size_t)(batch * CX + xq * 4)) * NSP + s0 + xh * 4;
#pragma unroll
      for (int dc = 0; dc < 4; ++dc) {
        float4 a = *(const float4*)(xp + (size_t)dc * NSP);
        vv[dc][0] = a.x; vv[dc][1] = a.y; vv[dc][2] = a.z; vv[dc][3] = a.w;
      }
#pragma unroll
      for (int j = 0; j < 4; ++j) {
        ushort4 o;
        o.x = f2bf(vv[0][j]); o.y = f2bf(vv[1][j]);
        o.z = f2bf(vv[2][j]); o.w = f2bf(vv[3][j]);
        *(ushort4*)&lX[(xh * 4 + j) * LXS + xq * 4] = o;
      }
    }
    __syncthreads();

#pragma unroll
    for (int nt = 0; nt < 4; ++nt) {
      const int srow = nt * 16 + l16;
      floatx4 aG = {0.f, 0.f, 0.f, 0.f};
      floatx4 aX = {0.f, 0.f, 0.f, 0.f};
#pragma unroll
      for (int kk = 0; kk < 4; ++kk) {
        short8 bfr = *(const short8*)&lG[srow * LGS + kk * 32 + quad * 8];
        aG = __builtin_amdgcn_mfma_f32_16x16x32_bf16(fg[kk], bfr, aG, 0, 0, 0);
      }
#pragma unroll
      for (int kk = 0; kk < 2; ++kk) {
        short8 bfr = *(const short8*)&lX[srow * LXS + kk * 32 + quad * 8];
        aX = __builtin_amdgcn_mfma_f32_16x16x32_bf16(fx[kk], bfr, aX, 0, 0, 0);
      }
#pragma unroll
      for (int r = 0; r < 4; ++r) {
        sumG += aG[r]; sqG += aG[r] * aG[r];
        sumX += aX[r]; sqX += aX[r] * aX[r];
      }
      // D layout: row(oc) = quad*4+r, col(spatial) = lane&15
      const int s = s0 + nt * 16 + l16;
      ushort4 og, ox;
      og.x = f2bf(aG[0]); og.y = f2bf(aG[1]); og.z = f2bf(aG[2]); og.w = f2bf(aG[3]);
      ox.x = f2bf(aX[0]); ox.y = f2bf(aX[1]); ox.z = f2bf(aX[2]); ox.w = f2bf(aX[3]);
      const size_t base = ((size_t)batch * NSP + s) * CO + ocb + quad * 4;
      *(ushort4*)(outg + base) = og;
      *(ushort4*)(outx + base) = ox;
    }
  }

  // all 4 values of a lane belong to group (4*wave + quad) >> 1;
  // lanes 0..31 -> group 2w, lanes 32..63 -> group 2w+1
#pragma unroll
  for (int m = 1; m <= 16; m <<= 1) {
    sumG += __shfl_xor(sumG, m); sqG += __shfl_xor(sqG, m);
    sumX += __shfl_xor(sumX, m); sqX += __shfl_xor(sqX, m);
  }
  if ((lane & 31) == 0) {
    const int grp = wave * 2 + (lane >> 5);
    float* sp = stats + ((size_t)batch * GROUPS + grp) * 4;
    atomicAdd(sp + 0, sumG); atomicAdd(sp + 1, sqG);
    atomicAdd(sp + 2, sumX); atomicAdd(sp + 3, sqX);
  }
}

// ---------------- K1.5: fold stats into per-(b,oc) constants ----------------
__global__ void k2_const(const float* __restrict__ stats,
                         const float* __restrict__ wgw, const float* __restrict__ wgb,
                         const float* __restrict__ wxw, const float* __restrict__ wxb,
                         const float* __restrict__ psiw, float4* __restrict__ cst)
{
  const int tid = threadIdx.x;
  if (tid >= 2 * CO) return;
  const int b = tid >> 6, oc = tid & 63, grp = oc >> 3;
  const float* sp = stats + ((size_t)b * GROUPS + grp) * 4;
  const float inv = 1.f / (float)(NSP * (CO / GROUPS));
  float mG = sp[0] * inv, vG = sp[1] * inv - mG * mG;
  float mX = sp[2] * inv, vX = sp[3] * inv - mX * mX;
  float rG = rsqrtf(vG + EPS), rX = rsqrtf(vX + EPS);
  float sG = wgw[oc] * rG, sX = wxw[oc] * rX;
  float bias = wgb[oc] - mG * sG + wxb[oc] - mX * sX;
  cst[b * CO + oc] = make_float4(sG, sX, bias, psiw[oc]);
}

// ---------------- K2: leaky(g1+x1) . psi_w  + psi stats ----------------
__global__ __launch_bounds__(256, 4)
void k3_gate(const unsigned short* __restrict__ ing,
             const unsigned short* __restrict__ inx,
             const float4* __restrict__ cst,
             float* __restrict__ ppre, float* __restrict__ psiSt)
{
  __shared__ float4 scst[CO];
  const int tid = threadIdx.x;
  const int batch = blockIdx.x >> 10;               // 1024 blocks per batch
  const int s = ((blockIdx.x & 1023) << 8) + tid;
  if (tid < CO) scst[tid] = cst[batch * CO + tid];
  __syncthreads();

  const size_t base = ((size_t)batch * NSP + s) * CO;
  uint4 rg[8], rx[8];
#pragma unroll
  for (int i = 0; i < 8; ++i) {
    rg[i] = ((const uint4*)(ing + base))[i];
    rx[i] = ((const uint4*)(inx + base))[i];
  }
  float p = 0.f;
  auto proc2 = [&](uint32_t gb, uint32_t xb, int oc) {
    float4 c0 = scst[oc], c1 = scst[oc + 1];
    float g0 = bf2f(gb & 0xffffu), g1 = bf2f(gb >> 16);
    float x0 = bf2f(xb & 0xffffu), x1 = bf2f(xb >> 16);
    float a0 = fmaf(g0, c0.x, fmaf(x0, c0.y, c0.z));
    float a1 = fmaf(g1, c1.x, fmaf(x1, c1.y, c1.z));
    a0 = (a0 >= 0.f) ? a0 : 0.01f * a0;
    a1 = (a1 >= 0.f) ? a1 : 0.01f * a1;
    p = fmaf(c0.w, a0, fmaf(c1.w, a1, p));
  };
#pragma unroll
  for (int i = 0; i < 8; ++i) {
    proc2(rg[i].x, rx[i].x, i * 8 + 0);
    proc2(rg[i].y, rx[i].y, i * 8 + 2);
    proc2(rg[i].z, rx[i].z, i * 8 + 4);
    proc2(rg[i].w, rx[i].w, i * 8 + 6);
  }
  ppre[(size_t)batch * NSP + s] = p;

  float ps = p, pq = p * p;
#pragma unroll
  for (int m = 1; m <= 32; m <<= 1) { ps += __shfl_xor(ps, m); pq += __shfl_xor(pq, m); }
  __shared__ float red[8];
  const int wave = tid >> 6, lane = tid & 63;
  if (lane == 0) { red[wave * 2] = ps; red[wave * 2 + 1] = pq; }
  __syncthreads();
  if (tid == 0) {
    float a0 = red[0] + red[2] + red[4] + red[6];
    float a1 = red[1] + red[3] + red[5] + red[7];
    atomicAdd(&psiSt[batch * 2 + 0], a0);
    atomicAdd(&psiSt[batch * 2 + 1], a1);
  }
}

// ---------------- K3: psi = sigmoid(GN(p)), out = x * psi ----------------
__global__ __launch_bounds__(256, 4)
void k4_out(const float* __restrict__ x, const float* __restrict__ ppre,
            const float* __restrict__ psiSt, const float* __restrict__ pgw,
            const float* __restrict__ pgb, float* __restrict__ out)
{
  const size_t q = (size_t)blockIdx.x * 256 + threadIdx.x;  // 8,388,608 threads
  const int s4 = (int)(q & (NSP / 4 - 1)) * 4;
  const int cb = (int)(q >> 16);   // NSP/4 = 65536
  const int c  = cb & 63;
  const int b  = cb >> 6;
  const float inv = 1.f / (float)NSP;
  const float mean = psiSt[b * 2] * inv;
  const float var  = psiSt[b * 2 + 1] * inv - mean * mean;
  const float rstd = rsqrtf(var + EPS);
  const float w0 = pgw[0], b0 = pgb[0];
  float4 p  = *(const float4*)&ppre[(size_t)b * NSP + s4];
  float4 xv = *(const float4*)&x[((size_t)(b * CX + c)) * NSP + s4];
  float4 o;
  o.x = xv.x / (1.f + __expf(-(fmaf((p.x - mean) * rstd, w0, b0))));
  o.y = xv.y / (1.f + __expf(-(fmaf((p.y - mean) * rstd, w0, b0))));
  o.z = xv.z / (1.f + __expf(-(fmaf((p.z - mean) * rstd, w0, b0))));
  o.w = xv.w / (1.f + __expf(-(fmaf((p.w - mean) * rstd, w0, b0))));
  *(float4*)&out[((size_t)(b * CX + c)) * NSP + s4] = o;
}

extern "C" void kernel_launch(void* const* d_in, const int* in_sizes, int n_in,
                              void* d_out, int out_size, void* d_ws, size_t ws_size,
                              hipStream_t stream)
{
  const float* g     = (const float*)d_in[0];
  const float* x     = (const float*)d_in[1];
  const float* wgw   = (const float*)d_in[2];   // Wg_w [64][128]
  const float* wggnw = (const float*)d_in[3];
  const float* wggnb = (const float*)d_in[4];
  const float* wxw   = (const float*)d_in[5];   // Wx_w [64][64]
  const float* wxgnw = (const float*)d_in[6];
  const float* wxgnb = (const float*)d_in[7];
  const float* psiw  = (const float*)d_in[8];   // [1][64]
  const float* psgnw = (const float*)d_in[9];
  const float* psgnb = (const float*)d_in[10];

  char* ws = (char*)d_ws;
  unsigned short* wsg = (unsigned short*)ws;                 // 67,108,864 B
  unsigned short* wsx = (unsigned short*)(ws + 67108864);    // 67,108,864 B
  float* ppre   = (float*)(ws + 134217728);                  // 2,097,152 B
  float* stats  = (float*)(ws + 136314880);                  // 256 B
  float* psiSt  = (float*)(ws + 136315136);                  // 16 B
  float4* cst   = (float4*)(ws + 136315200);                 // 2048 B

  hipMemsetAsync(ws + 136314880, 0, 320, stream);  // stats + psiStats

  hipLaunchKernelGGL(k1_conv, dim3(1024), dim3(256), 0, stream,
                     g, x, wgw, wxw, wsg, wsx, stats);
  hipLaunchKernelGGL(k2_const, dim3(1), dim3(128), 0, stream,
                     stats, wggnw, wggnb, wxgnw, wxgnb, psiw, cst);
  hipLaunchKernelGGL(k3_gate, dim3(2048), dim3(256), 0, stream,
                     wsg, wsx, cst, ppre, psiSt);
  hipLaunchKernelGGL(k4_out, dim3(32768), dim3(256), 0, stream,
                     x, ppre, psiSt, psgnw, psgnb, (float*)d_out);
}